// Round 4
// baseline (3285.467 us; speedup 1.0000x reference)
//
#include <hip/hip_runtime.h>
#include <hip/hip_bf16.h>

typedef __hip_bfloat16 bf16;
typedef __attribute__((ext_vector_type(8))) short short8;
typedef __attribute__((ext_vector_type(4))) float f32x4;

__device__ __forceinline__ float b2f(const bf16 v){ return __bfloat162float(v); }
__device__ __forceinline__ float ld(const float* p, long i){ return p[i]; }
__device__ __forceinline__ float ld(const bf16*  p, long i){ return b2f(p[i]); }

__device__ __forceinline__ unsigned f2bf_u(float f){
    union { float f; unsigned u; } a; a.f = f;
    unsigned r = a.u + 0x7FFFu + ((a.u >> 16) & 1u);
    return r >> 16;
}

// ---- converted-params block offsets (floats) within P ----
#define OFF_C1W   0        /* 11616 */
#define OFF_C1B   11616    /* 32   */
#define OFF_RLG   11648    /* 2048 */
#define OFF_RLB   13696
#define OFF_RLM   15744
#define OFF_RLV   17792
#define OFF_RLCW  19840    /* 589824 slots: reused as bf16 WB [net][ci][tap][c] */
#define OFF_RLCB  609664   /* 2048 */
#define OFF_BNG   611712
#define OFF_BNB   611744
#define OFF_BNM   611776
#define OFF_BNV   611808
#define OFF_C2W   611840   /* 32768 (f32, unused by conv2 now) */
#define OFF_C2B   644608
#define OFF_C3W   644624   /* 16384 (f32, unused by conv3 now) */
#define OFF_C3B   661008
#define OFF_C4W   661024   /* 9216 */
#define OFF_C4B   670240
#define OFF_C5W   670256   /* 6400 */
#define OFF_C5B   676656
#define OFF_F1B   676672   /* 4096 */
#define OFF_F2B   680768   /* 2048 */
#define OFF_F3B   682816   /* 24   */
#define P_TOTAL   682840
#define OFF_WB2   P_TOTAL             /* 32768 bf16 = 16384 f32 slots */
#define OFF_WB3   (P_TOTAL + 16384)   /* 16384 bf16 = 8192 f32 slots  */
#define P_END     (P_TOTAL + 16384 + 8192)

#define SZ_RL  589824
#define SZ_WB2 32768
#define SZ_WB3 16384

// ---------- dtype sniff: flag=1 if inputs are float32, 0 if bf16 ----------
__global__ void k_sniff(const void* __restrict__ x, int* __restrict__ flag)
{
    const bf16* xb = (const bf16*)x;
    const float v = fabsf(b2f(xb[2*threadIdx.x]));
    const int ok = (v >= 1e-6f && v <= 1e6f) ? 1 : 0;
    __shared__ int cnt;
    if (threadIdx.x == 0) cnt = 0;
    __syncthreads();
    atomicAdd(&cnt, ok);
    __syncthreads();
    if (threadIdx.x == 0) *flag = (cnt >= 192) ? 0 : 1;
}

// ---------- convert params to f32 block P + bf16 fragment-layout weight blocks ----------
struct CvtArgs { const void* src[23]; int off[23]; const void* cw; const void* w2; const void* w3; int total; };

__device__ __forceinline__ float getv(const void* p, long i, bool isf){
    return isf ? ((const float*)p)[i] : b2f(((const bf16*)p)[i]);
}

__global__ __launch_bounds__(256) void k_cvt(CvtArgs a, const int* __restrict__ flag,
                                             float* __restrict__ P)
{
    const bool isf = (*flag != 0);
    const int i1 = a.total;            // region WB (bf16, in rl_cw slot)
    const int i2 = i1 + SZ_RL;         // WB2
    const int i3 = i2 + SZ_WB2;        // WB3
    const int i4 = i3 + SZ_WB3;
    for (int idx = blockIdx.x*256 + threadIdx.x; idx < i4; idx += gridDim.x*256){
        if (idx < i1){
            if (idx >= OFF_RLCW && idx < OFF_RLCB) continue;   // slot reused for WB
            int k = 0;
            #pragma unroll
            for (int j = 1; j < 23; j++) if (idx >= a.off[j]) k = j;
            P[idx] = getv(a.src[k], idx - a.off[k], isf);
        } else if (idx < i2){
            // WB[net][ci][tap][c] <- rl_cw[net][c][ci][tap], bf16
            const int d = idx - i1;
            const int c = d & 31, q = d >> 5;
            const int tap = q % 9, r = q / 9;
            const int ci = r & 31, net = r >> 5;
            const long sidx = (long)((net*32 + c)*32 + ci)*9 + tap;
            ((unsigned short*)(P + OFF_RLCW))[d] = (unsigned short)f2bf_u(getv(a.cw, sidx, isf));
        } else if (idx < i3){
            // WB2[tap][lane][j]: B-fragment layout for conv2 (K=32ci)
            const int d = idx - i2;
            const int j = d & 7, lane = (d >> 3) & 63, tap = d >> 9;
            const int n = lane & 15, k = ((lane >> 4) << 3) + j;
            const int ci = k, ky = tap >> 3, kx = tap & 7;
            const long sidx = (long)((n*32 + ci)*8 + ky)*8 + kx;
            ((unsigned short*)(P + OFF_WB2))[d] = (unsigned short)f2bf_u(getv(a.w2, sidx, isf));
        } else {
            // WB3[pair][lane][j]: B-fragment layout for conv3 (K=16ci x 2 taps)
            const int d = idx - i3;
            const int j = d & 7, lane = (d >> 3) & 63, pair = d >> 9;
            const int n = lane & 15, k = ((lane >> 4) << 3) + j;
            const int tsel = k >> 4, ci = k & 15;
            const int ky = pair >> 2, kx = ((pair & 3) << 1) + tsel;
            const long sidx = (long)((n*16 + ci)*8 + ky)*8 + kx;
            ((unsigned short*)(P + OFF_WB3))[d] = (unsigned short)f2bf_u(getv(a.w3, sidx, isf));
        }
    }
}

// ---------------- conv1 v2: x[32,3,170,170] -> [32,32,160,160], k=11 ----------------
__global__ __launch_bounds__(256,3) void k_conv1(const void* __restrict__ x,
        const int* __restrict__ flag, const float* __restrict__ P, float* __restrict__ out)
{
    __shared__ float xs[3*14*176];     // 29,568 B
    __shared__ float wsm[363*16];      // 23,232 B  [tap][co16]
    const int t = threadIdx.x;
    const int rg = blockIdx.x, b = blockIdx.y, half = blockIdx.z;
    const int y0 = rg*4;
    for (int e=t; e<5808; e+=256){
        const int co_l = e & 15, tap = e >> 4;
        wsm[tap*16 + co_l] = P[OFF_C1W + (half*16+co_l)*363 + tap];
    }
    const bool isf = (*flag) != 0;
    if (isf){
        const float* xf = (const float*)x;
        for (int e=t; e<7140; e+=256){
            const int ci = e/2380, rem = e%2380, r = rem/170, col = rem%170;
            xs[(ci*14+r)*176 + col] = xf[((long)(b*3+ci)*170 + y0+r)*170 + col];
        }
    } else {
        const bf16* xf = (const bf16*)x;
        for (int e=t; e<7140; e+=256){
            const int ci = e/2380, rem = e%2380, r = rem/170, col = rem%170;
            xs[(ci*14+r)*176 + col] = b2f(xf[((long)(b*3+ci)*170 + y0+r)*170 + col]);
        }
    }
    __syncthreads();
    const int co_l = t & 15, xg = t >> 4;
    const int co = half*16 + co_l;
    float acc[4][10];
    const float bv = P[OFF_C1B + co];
    #pragma unroll
    for (int r=0;r<4;r++)
        #pragma unroll
        for (int j=0;j<10;j++) acc[r][j]=bv;
    for (int ci=0; ci<3; ci++){
        #pragma unroll 1
        for (int ir=0; ir<14; ir++){
            float xv[20];
            #pragma unroll
            for (int j=0;j<20;j++) xv[j] = xs[(ci*14+ir)*176 + xg*10 + j];
            const int rlo = (ir>10)? ir-10 : 0;
            const int rhi = (ir<3)? ir : 3;
            #pragma unroll
            for (int r=0;r<4;r++){
                if (r < rlo || r > rhi) continue;
                const int ky = ir - r;
                const float* wrow = &wsm[(ci*121 + ky*11)*16 + co_l];
                #pragma unroll
                for (int kx=0;kx<11;kx++){
                    const float wv = wrow[kx*16];
                    #pragma unroll
                    for (int j=0;j<10;j++) acc[r][j] = fmaf(xv[j+kx], wv, acc[r][j]);
                }
            }
        }
    }
    #pragma unroll
    for (int r=0;r<4;r++){
        float* op = out + (((long)b*32+co)*160 + y0+r)*160 + xg*10;
        #pragma unroll
        for (int j=0;j<10;j++) op[j] = acc[r][j];
    }
}

// ------- region layer fused relu+maxpool2+bn; block = (patch, batch, row-half) -------
__global__ __launch_bounds__(256,3) void k_region_pool(const float* __restrict__ in,
        const float* __restrict__ P, float* __restrict__ pooled)
{
    __shared__ float s[32*12*22];       // 33,792 B
    __shared__ bf16  wsm[32*9*32];      // 18,432 B  [ci][tap][c]
    __shared__ float sc[32], sh[32];
    const int t = threadIdx.x;
    const int bx = blockIdx.x;
    const int h  = bx & 1;
    const int b  = (bx >> 1) & 31;
    const int kk = bx >> 6;
    const int gi = kk >> 3, gj = kk & 7;
    const int net = gj * (gi + 1);      // idx = ii*jj + jj
    const int ibase = (b*32*160 + gi*20)*160 + gj*20;
    { const uint* src = (const uint*)((const bf16*)(P + OFF_RLCW) + net*9216);
      uint* dst = (uint*)wsm;
      for (int j=t; j<4608; j+=256) dst[j] = src[j]; }
    if (t < 32){
        const float inv = rsqrtf(P[OFF_RLV + net*32+t] + 1e-5f) * P[OFF_RLG + net*32+t];
        sc[t] = inv;
        sh[t] = P[OFF_RLB + net*32+t] - P[OFF_RLM + net*32+t]*inv;
    }
    for (int j=t; j<8448; j+=256) s[j] = 0.f;
    __syncthreads();
    const int p0 = h*9, sr0 = 1-h;
    for (int e=t; e<7040; e+=256){
        const int ci = e/220, rem = e%220, rr = rem/20, col = rem%20;
        const float v = in[ibase + ci*25600 + (p0+rr)*160 + col];
        s[ci*264 + (sr0+rr)*22 + (col+1)] = fmaxf(fmaf(v, sc[ci], sh[ci]), 0.f);
    }
    __syncthreads();
    const int c = t & 31, tile = t >> 5;
    const int r0 = (tile >> 2)*5, c0 = (tile & 3)*5;
    float acc[5][5];
    { const float bv = P[OFF_RLCB + net*32 + c];
      #pragma unroll
      for (int rr=0;rr<5;rr++)
          #pragma unroll
          for (int cc=0;cc<5;cc++) acc[rr][cc]=bv; }
    #pragma unroll 1
    for (int ci=0; ci<32; ci++){
        float win[7][7];
        const float* sp = &s[ci*264 + r0*22 + c0];
        #pragma unroll
        for (int i7=0;i7<7;i7++)
            #pragma unroll
            for (int j7=0;j7<7;j7++) win[i7][j7] = sp[i7*22+j7];
        float wv[9];
        const bf16* wp = &wsm[ci*288 + c];
        #pragma unroll
        for (int q=0;q<9;q++) wv[q] = b2f(wp[q*32]);
        #pragma unroll
        for (int rr=0;rr<5;rr++)
            #pragma unroll
            for (int dy=0;dy<3;dy++)
                #pragma unroll
                for (int dx=0;dx<3;dx++){
                    const float wq = wv[dy*3+dx];
                    #pragma unroll
                    for (int cc=0;cc<5;cc++)
                        acc[rr][cc] = fmaf(win[rr+dy][cc+dx], wq, acc[rr][cc]);
                }
    }
    __syncthreads();
    {
        const int obase = ibase + c*25600 + (h*10 + r0)*160 + c0;
        #pragma unroll
        for (int rr=0;rr<5;rr++)
            #pragma unroll
            for (int cc=0;cc<5;cc++)
                s[c*200 + (r0+rr)*20 + (c0+cc)] = acc[rr][cc] + in[obase + rr*160 + cc];
    }
    __syncthreads();
    for (int e=t; e<1600; e+=256){
        const int c2 = e/50, rem = e%50, pr = rem/10, pc = rem%10;
        const float* sp = &s[c2*200 + (2*pr)*20 + 2*pc];
        float m = fmaxf(fmaxf(sp[0],sp[1]), fmaxf(sp[20],sp[21]));
        m = fmaxf(m, 0.f);
        const float inv = rsqrtf(P[OFF_BNV + c2] + 1e-5f) * P[OFF_BNG + c2];
        pooled[((b*32+c2)*80 + gi*10 + h*5 + pr)*80 + gj*10 + pc] =
            fmaf(m - P[OFF_BNM + c2], inv, P[OFF_BNB + c2]);
    }
}

// ------- conv2/conv3 via MFMA shift-GEMM: one 16x16x32 MFMA per (16-pix tile, K-chunk) -------
// C[pix16, co16] += X[pix16, k32] * W[k32, co16];  conv2: k=ci32 per tap; conv3: k=2taps x ci16
template<int CIN, int HIN, int WIN, int HOUT, int WOUT>
__global__ __launch_bounds__(256) void k_convM(const float* __restrict__ in,
        const unsigned short* __restrict__ WB, const float* __restrict__ bias,
        float* __restrict__ out)
{
    constexpr int PP = 23;
    constexpr bool C32 = (CIN == 32);
    __shared__ unsigned short xs[PP*PP*CIN];           // [pix][ci] bf16
    __shared__ unsigned short ws[C32 ? 16*64*8 : 32*64*8];
    const int t = threadIdx.x;
    const int col0 = blockIdx.x*16, row0 = blockIdx.y*16, b = blockIdx.z;
    // stage x patch: 2 adjacent ci per thread -> packed b32 LDS write (conflict-free)
    for (int e = t; e < PP*PP*(CIN/2); e += 256){
        const int ci2 = e % (CIN/2), pix = e / (CIN/2);
        int rr = row0 + pix/PP; if (rr > HIN-1) rr = HIN-1;
        int cc = col0 + pix%PP; if (cc > WIN-1) cc = WIN-1;
        const float* gp = &in[((long)(b*CIN + 2*ci2)*HIN + rr)*WIN + cc];
        const unsigned lo = f2bf_u(gp[0]);
        const unsigned hi = f2bf_u(gp[(long)HIN*WIN]);
        ((unsigned*)xs)[pix*(CIN/2) + ci2] = lo | (hi << 16);
    }
    const int wave = t>>6, lane = t&63;
    const int quad = lane>>4, n16 = lane&15;
    const float bv = bias[n16];
    f32x4 acc[4];
    #pragma unroll
    for (int mt=0;mt<4;mt++) acc[mt] = (f32x4){bv,bv,bv,bv};
    if constexpr (C32){
        for (int ch=0; ch<4; ch++){
            __syncthreads();
            const unsigned* src = (const unsigned*)WB + ch*4096;
            for (int e=t; e<4096; e+=256) ((unsigned*)ws)[e] = src[e];
            __syncthreads();
            #pragma unroll 1
            for (int tap=0; tap<16; tap++){
                const int tg = ch*16+tap, ky = tg>>3, kx = tg&7;
                const short8 bw = *(const short8*)&ws[(tap*64+lane)*8];
                #pragma unroll
                for (int mt=0; mt<4; mt++){
                    const int pr = wave*4+mt+ky, pc = n16+kx;
                    const short8 av = *(const short8*)&xs[(pr*PP+pc)*32 + quad*8];
                    acc[mt] = __builtin_amdgcn_mfma_f32_16x16x32_bf16(av, bw, acc[mt], 0,0,0);
                }
            }
        }
    } else {
        for (int e=t; e<8192; e+=256) ((unsigned*)ws)[e] = ((const unsigned*)WB)[e];
        __syncthreads();
        #pragma unroll 1
        for (int pair=0; pair<32; pair++){
            const int ky = pair>>2, kx0 = (pair&3)*2;
            const short8 bw = *(const short8*)&ws[(pair*64+lane)*8];
            #pragma unroll
            for (int mt=0; mt<4; mt++){
                const int pr = wave*4+mt+ky, pc = n16 + kx0 + (quad>>1);
                const short8 av = *(const short8*)&xs[(pr*PP+pc)*16 + (quad&1)*8];
                acc[mt] = __builtin_amdgcn_mfma_f32_16x16x32_bf16(av, bw, acc[mt], 0,0,0);
            }
        }
    }
    // D: co = lane&15, pixel-col = quad*4 + reg; relu + store
    #pragma unroll
    for (int mt=0; mt<4; mt++){
        const int orow = row0 + wave*4 + mt;
        if (orow >= HOUT) continue;
        const int ocol = col0 + quad*4;
        float* op = out + ((long)(b*16 + n16)*HOUT + orow)*WOUT + ocol;
        #pragma unroll
        for (int r=0;r<4;r++){
            if (ocol + r < WOUT) op[r] = fmaxf(acc[mt][r], 0.f);
        }
    }
}

// ---------------- generic direct conv (+relu) for the small conv4/conv5 ----------------
template<int CIN, int COUT, int KS, int STRIDE, int HIN, int WIN, int HOUT, int WOUT, int NG>
__global__ __launch_bounds__(256) void k_convN(const float* __restrict__ in,
        const float* __restrict__ w, const float* __restrict__ bias, float* __restrict__ out)
{
    __shared__ float wl[CIN*KS*KS];
    const int co = blockIdx.y, b = blockIdx.z;
    for (int j=threadIdx.x; j<CIN*KS*KS; j+=blockDim.x) wl[j] = w[co*CIN*KS*KS + j];
    __syncthreads();
    const int i = blockIdx.x*blockDim.x + threadIdx.x;
    if (i >= HOUT*NG) return;
    const int y = i / NG, x0 = (i % NG) * 8;
    float acc[8];
    const float bv = bias[co];
    #pragma unroll
    for (int j=0;j<8;j++) acc[j]=bv;
    constexpr int SPAN = STRIDE*7 + KS;
    for (int ci=0; ci<CIN; ci++){
        #pragma unroll 1
        for (int ky=0; ky<KS; ky++){
            const float* ip = in + ((b*CIN+ci)*HIN + (STRIDE*y+ky))*WIN + STRIDE*x0;
            float v[SPAN];
            #pragma unroll
            for (int j=0;j<SPAN;j++) v[j]=ip[j];
            const float* wr = &wl[(ci*KS+ky)*KS];
            #pragma unroll
            for (int kx=0;kx<KS;kx++){
                const float wv = wr[kx];
                #pragma unroll
                for (int j=0;j<8;j++) acc[j] = fmaf(v[STRIDE*j+kx], wv, acc[j]);
            }
        }
    }
    float* op = out + ((b*COUT+co)*HOUT + y)*WOUT + x0;
    #pragma unroll
    for (int j=0;j<8;j++){
        if (x0 + j < WOUT) op[j] = fmaxf(acc[j], 0.f);
    }
}

// ---------------- FC: 8 outputs/block, coalesced 32-wide k stripes ----------------
template<typename T>
__device__ __forceinline__ void fc8_dot(const float* __restrict__ x, const T* __restrict__ w,
        const int K, const int o, const int kg, float* acc)
{
    const T* wp = w + (long)o*K;
    for (int k=kg; k<K; k+=32){
        const float wv = ld(wp, k);
        #pragma unroll
        for (int b=0;b<32;b++) acc[b] = fmaf(x[b*K+k], wv, acc[b]);
    }
}

__global__ __launch_bounds__(256) void k_fc8(const float* __restrict__ x,
        const void* __restrict__ w, const float* __restrict__ bias,
        const int* __restrict__ flag, float* __restrict__ y, int K, int N, int do_relu)
{
    const int t = threadIdx.x;
    const int ol = t >> 5, kg = t & 31;
    const int o = blockIdx.x*8 + ol;
    float acc[32];
    #pragma unroll
    for (int b=0;b<32;b++) acc[b]=0.f;
    if (*flag) fc8_dot<float>(x, (const float*)w, K, o, kg, acc);
    else       fc8_dot<bf16 >(x, (const bf16 *)w, K, o, kg, acc);
    __shared__ float p[8][32];
    const int lane = t & 63;
    #pragma unroll
    for (int b=0;b<32;b++){
        float v = acc[b];
        v += __shfl_down(v, 16, 64);
        v += __shfl_down(v, 8, 64);
        v += __shfl_down(v, 4, 64);
        v += __shfl_down(v, 2, 64);
        v += __shfl_down(v, 1, 64);
        if ((lane & 31) == 0) p[ol][b] = v;
    }
    __syncthreads();
    if (t < 256){
        const int b = t >> 3, oo = t & 7;
        float s = p[oo][b] + bias[blockIdx.x*8 + oo];
        if (do_relu) s = fmaxf(s, 0.f);
        y[b*N + blockIdx.x*8 + oo] = s;
    }
}

// ---------------- paired log_softmax over axis 1 of [32,2,12] ----------------
__global__ void k_lsm(const float* __restrict__ in, const int* __restrict__ flag,
                      void* __restrict__ out)
{
    const int i = threadIdx.x;
    if (i >= 384) return;
    const int b = i/12, au = i%12;
    const float a0 = in[b*24+au], a1 = in[b*24+12+au];
    const float m = fmaxf(a0,a1);
    const float lse = m + logf(expf(a0-m)+expf(a1-m));
    const float o0 = a0-lse, o1 = a1-lse;
    if (*flag){
        ((float*)out)[b*24+au]    = o0;
        ((float*)out)[b*24+12+au] = o1;
    } else {
        ((bf16*)out)[b*24+au]    = __float2bfloat16(o0);
        ((bf16*)out)[b*24+12+au] = __float2bfloat16(o1);
    }
}

extern "C" void kernel_launch(void* const* d_in, const int* in_sizes, int n_in,
                              void* d_out, int out_size, void* d_ws, size_t ws_size,
                              hipStream_t stream) {
    (void)in_sizes; (void)n_in; (void)out_size; (void)ws_size;
    const void* x = d_in[0];

    float* A = (float*)d_ws;               // 26,214,400 floats
    float* B = A + 26214400;               //  6,553,600 floats
    float* P = B + 6553600;                //  P_END floats
    int* flag = (int*)(P + P_END);

    CvtArgs a;
    const int src_idx[23] = {1,2,3,4,5,6,7,8,9,10,11,12,13,14,15,16,17,18,19,20,22,24,26};
    const int offs[23] = {OFF_C1W,OFF_C1B,OFF_RLG,OFF_RLB,OFF_RLM,OFF_RLV,OFF_RLCW,OFF_RLCB,
                          OFF_BNG,OFF_BNB,OFF_BNM,OFF_BNV,OFF_C2W,OFF_C2B,OFF_C3W,OFF_C3B,
                          OFF_C4W,OFF_C4B,OFF_C5W,OFF_C5B,OFF_F1B,OFF_F2B,OFF_F3B};
    for (int j=0;j<23;j++){ a.src[j] = d_in[src_idx[j]]; a.off[j] = offs[j]; }
    a.cw = d_in[7]; a.w2 = d_in[13]; a.w3 = d_in[15];
    a.total = P_TOTAL;

    k_sniff<<<1,256,0,stream>>>(x, flag);
    k_cvt<<<(P_TOTAL+SZ_RL+SZ_WB2+SZ_WB3+255)/256,256,0,stream>>>(a, flag, P);
    k_conv1<<<dim3(40,32,2),256,0,stream>>>(x, flag, P, A);
    k_region_pool<<<4096,256,0,stream>>>(A, P, B);
    // conv2: [32,32,80,80] -> [32,16,73,73]  (MFMA)
    k_convM<32,80,80,73,73><<<dim3(5,5,32),256,0,stream>>>(B, (const unsigned short*)(P+OFF_WB2), P+OFF_C2B, A);
    // conv3: -> [32,16,66,66]  (MFMA)
    k_convM<16,73,73,66,66><<<dim3(5,5,32),256,0,stream>>>(A, (const unsigned short*)(P+OFF_WB3), P+OFF_C3B, B);
    // conv4: stride 2 -> [32,16,31,31]
    k_convN<16,16,6,2,66,66,31,31,4><<<dim3(1,16,32),128,0,stream>>>(B, P+OFF_C4W, P+OFF_C4B, A);
    // conv5: -> [32,16,27,27]
    k_convN<16,16,5,1,31,31,27,27,4><<<dim3(1,16,32),128,0,stream>>>(A, P+OFF_C5W, P+OFF_C5B, B);
    // fc1: K=11664 -> 4096 (relu)
    k_fc8<<<512,256,0,stream>>>(B, d_in[21], P+OFF_F1B, flag, A, 11664, 4096, 1);
    // fc2: 4096 -> 2048 (relu)
    k_fc8<<<256,256,0,stream>>>(A, d_in[23], P+OFF_F2B, flag, B, 4096, 2048, 1);
    // fc3: 2048 -> 24
    k_fc8<<<3,256,0,stream>>>(B, d_in[25], P+OFF_F3B, flag, A, 2048, 24, 0);
    k_lsm<<<1,384,0,stream>>>(A, flag, d_out);
}

// Round 5
// 1070.861 us; speedup vs baseline: 3.0681x; 3.0681x over previous
//
#include <hip/hip_runtime.h>
#include <hip/hip_bf16.h>

typedef __hip_bfloat16 bf16;
typedef __attribute__((ext_vector_type(8))) short short8;
typedef __attribute__((ext_vector_type(4))) float f32x4;

__device__ __forceinline__ float b2f(const bf16 v){ return __bfloat162float(v); }
__device__ __forceinline__ float ld(const float* p, long i){ return p[i]; }
__device__ __forceinline__ float ld(const bf16*  p, long i){ return b2f(p[i]); }

__device__ __forceinline__ unsigned f2bf_u(float f){
    union { float f; unsigned u; } a; a.f = f;
    unsigned r = a.u + 0x7FFFu + ((a.u >> 16) & 1u);
    return r >> 16;
}

__device__ __forceinline__ short8 pack8(const float* v){
    union { unsigned u[4]; short8 s; } r;
    r.u[0] = f2bf_u(v[0]) | (f2bf_u(v[1])<<16);
    r.u[1] = f2bf_u(v[2]) | (f2bf_u(v[3])<<16);
    r.u[2] = f2bf_u(v[4]) | (f2bf_u(v[5])<<16);
    r.u[3] = f2bf_u(v[6]) | (f2bf_u(v[7])<<16);
    return r.s;
}

// ---- converted-params block offsets (floats) within P ----
#define OFF_C1W   0        /* 11616 */
#define OFF_C1B   11616    /* 32   */
#define OFF_RLG   11648    /* 2048 */
#define OFF_RLB   13696
#define OFF_RLM   15744
#define OFF_RLV   17792
#define OFF_RLCW  19840    /* 589824 slots: reused as bf16 WB [net][ci][tap][c] */
#define OFF_RLCB  609664   /* 2048 */
#define OFF_BNG   611712
#define OFF_BNB   611744
#define OFF_BNM   611776
#define OFF_BNV   611808
#define OFF_C2W   611840   /* 32768 (f32, unused by conv2 now) */
#define OFF_C2B   644608
#define OFF_C3W   644624   /* 16384 (f32, unused by conv3 now) */
#define OFF_C3B   661008
#define OFF_C4W   661024   /* 9216 */
#define OFF_C4B   670240
#define OFF_C5W   670256   /* 6400 */
#define OFF_C5B   676656
#define OFF_F1B   676672   /* 4096 */
#define OFF_F2B   680768   /* 2048 */
#define OFF_F3B   682816   /* 24   */
#define P_TOTAL   682840
#define OFF_WB2   P_TOTAL             /* 32768 bf16 = 16384 f32 slots */
#define OFF_WB3   (P_TOTAL + 16384)   /* 16384 bf16 = 8192 f32 slots  */
#define P_END     (P_TOTAL + 16384 + 8192)

#define SZ_RL  589824
#define SZ_WB2 32768
#define SZ_WB3 16384

// ---------- dtype sniff: flag=1 if inputs are float32, 0 if bf16 ----------
__global__ void k_sniff(const void* __restrict__ x, int* __restrict__ flag)
{
    const bf16* xb = (const bf16*)x;
    const float v = fabsf(b2f(xb[2*threadIdx.x]));
    const int ok = (v >= 1e-6f && v <= 1e6f) ? 1 : 0;
    __shared__ int cnt;
    if (threadIdx.x == 0) cnt = 0;
    __syncthreads();
    atomicAdd(&cnt, ok);
    __syncthreads();
    if (threadIdx.x == 0) *flag = (cnt >= 192) ? 0 : 1;
}

// ---------- convert params to f32 block P + bf16 fragment-layout weight blocks ----------
struct CvtArgs { const void* src[23]; int off[23]; const void* cw; const void* w2; const void* w3; int total; };

__device__ __forceinline__ float getv(const void* p, long i, bool isf){
    return isf ? ((const float*)p)[i] : b2f(((const bf16*)p)[i]);
}

__global__ __launch_bounds__(256) void k_cvt(CvtArgs a, const int* __restrict__ flag,
                                             float* __restrict__ P)
{
    const bool isf = (*flag != 0);
    const int i1 = a.total;            // region WB (bf16, in rl_cw slot)
    const int i2 = i1 + SZ_RL;         // WB2
    const int i3 = i2 + SZ_WB2;        // WB3
    const int i4 = i3 + SZ_WB3;
    for (int idx = blockIdx.x*256 + threadIdx.x; idx < i4; idx += gridDim.x*256){
        if (idx < i1){
            if (idx >= OFF_RLCW && idx < OFF_RLCB) continue;   // slot reused for WB
            int k = 0;
            #pragma unroll
            for (int j = 1; j < 23; j++) if (idx >= a.off[j]) k = j;
            P[idx] = getv(a.src[k], idx - a.off[k], isf);
        } else if (idx < i2){
            // WB[net][ci][tap][c] <- rl_cw[net][c][ci][tap], bf16
            const int d = idx - i1;
            const int c = d & 31, q = d >> 5;
            const int tap = q % 9, r = q / 9;
            const int ci = r & 31, net = r >> 5;
            const long sidx = (long)((net*32 + c)*32 + ci)*9 + tap;
            ((unsigned short*)(P + OFF_RLCW))[d] = (unsigned short)f2bf_u(getv(a.cw, sidx, isf));
        } else if (idx < i3){
            // WB2[tap][lane][j]: B-fragment layout for conv2 (K=32ci)
            const int d = idx - i2;
            const int j = d & 7, lane = (d >> 3) & 63, tap = d >> 9;
            const int n = lane & 15, k = ((lane >> 4) << 3) + j;
            const int ci = k, ky = tap >> 3, kx = tap & 7;
            const long sidx = (long)((n*32 + ci)*8 + ky)*8 + kx;
            ((unsigned short*)(P + OFF_WB2))[d] = (unsigned short)f2bf_u(getv(a.w2, sidx, isf));
        } else {
            // WB3[pair][lane][j]: B-fragment layout for conv3 (K=16ci x 2 taps)
            const int d = idx - i3;
            const int j = d & 7, lane = (d >> 3) & 63, pair = d >> 9;
            const int n = lane & 15, k = ((lane >> 4) << 3) + j;
            const int tsel = k >> 4, ci = k & 15;
            const int ky = pair >> 2, kx = ((pair & 3) << 1) + tsel;
            const long sidx = (long)((n*16 + ci)*8 + ky)*8 + kx;
            ((unsigned short*)(P + OFF_WB3))[d] = (unsigned short)f2bf_u(getv(a.w3, sidx, isf));
        }
    }
}

// ---------------- conv1 v2: x[32,3,170,170] -> [32,32,160,160], k=11 ----------------
__global__ __launch_bounds__(256,3) void k_conv1(const void* __restrict__ x,
        const int* __restrict__ flag, const float* __restrict__ P, float* __restrict__ out)
{
    __shared__ float xs[3*14*176];     // 29,568 B
    __shared__ float wsm[363*16];      // 23,232 B  [tap][co16]
    const int t = threadIdx.x;
    const int rg = blockIdx.x, b = blockIdx.y, half = blockIdx.z;
    const int y0 = rg*4;
    for (int e=t; e<5808; e+=256){
        const int co_l = e & 15, tap = e >> 4;
        wsm[tap*16 + co_l] = P[OFF_C1W + (half*16+co_l)*363 + tap];
    }
    const bool isf = (*flag) != 0;
    if (isf){
        const float* xf = (const float*)x;
        for (int e=t; e<7140; e+=256){
            const int ci = e/2380, rem = e%2380, r = rem/170, col = rem%170;
            xs[(ci*14+r)*176 + col] = xf[((long)(b*3+ci)*170 + y0+r)*170 + col];
        }
    } else {
        const bf16* xf = (const bf16*)x;
        for (int e=t; e<7140; e+=256){
            const int ci = e/2380, rem = e%2380, r = rem/170, col = rem%170;
            xs[(ci*14+r)*176 + col] = b2f(xf[((long)(b*3+ci)*170 + y0+r)*170 + col]);
        }
    }
    __syncthreads();
    const int co_l = t & 15, xg = t >> 4;
    const int co = half*16 + co_l;
    float acc[4][10];
    const float bv = P[OFF_C1B + co];
    #pragma unroll
    for (int r=0;r<4;r++)
        #pragma unroll
        for (int j=0;j<10;j++) acc[r][j]=bv;
    for (int ci=0; ci<3; ci++){
        #pragma unroll 1
        for (int ir=0; ir<14; ir++){
            float xv[20];
            #pragma unroll
            for (int j=0;j<20;j++) xv[j] = xs[(ci*14+ir)*176 + xg*10 + j];
            const int rlo = (ir>10)? ir-10 : 0;
            const int rhi = (ir<3)? ir : 3;
            #pragma unroll
            for (int r=0;r<4;r++){
                if (r < rlo || r > rhi) continue;
                const int ky = ir - r;
                const float* wrow = &wsm[(ci*121 + ky*11)*16 + co_l];
                #pragma unroll
                for (int kx=0;kx<11;kx++){
                    const float wv = wrow[kx*16];
                    #pragma unroll
                    for (int j=0;j<10;j++) acc[r][j] = fmaf(xv[j+kx], wv, acc[r][j]);
                }
            }
        }
    }
    #pragma unroll
    for (int r=0;r<4;r++){
        float* op = out + (((long)b*32+co)*160 + y0+r)*160 + xg*10;
        #pragma unroll
        for (int j=0;j<10;j++) op[j] = acc[r][j];
    }
}

// ------- region layer fused relu+maxpool2+bn; block = (patch, batch, row-half) -------
__global__ __launch_bounds__(256,3) void k_region_pool(const float* __restrict__ in,
        const float* __restrict__ P, float* __restrict__ pooled)
{
    __shared__ float s[32*12*22];       // 33,792 B
    __shared__ bf16  wsm[32*9*32];      // 18,432 B  [ci][tap][c]
    __shared__ float sc[32], sh[32];
    const int t = threadIdx.x;
    const int bx = blockIdx.x;
    const int h  = bx & 1;
    const int b  = (bx >> 1) & 31;
    const int kk = bx >> 6;
    const int gi = kk >> 3, gj = kk & 7;
    const int net = gj * (gi + 1);      // idx = ii*jj + jj
    const int ibase = (b*32*160 + gi*20)*160 + gj*20;
    { const uint* src = (const uint*)((const bf16*)(P + OFF_RLCW) + net*9216);
      uint* dst = (uint*)wsm;
      for (int j=t; j<4608; j+=256) dst[j] = src[j]; }
    if (t < 32){
        const float inv = rsqrtf(P[OFF_RLV + net*32+t] + 1e-5f) * P[OFF_RLG + net*32+t];
        sc[t] = inv;
        sh[t] = P[OFF_RLB + net*32+t] - P[OFF_RLM + net*32+t]*inv;
    }
    for (int j=t; j<8448; j+=256) s[j] = 0.f;
    __syncthreads();
    const int p0 = h*9, sr0 = 1-h;
    for (int e=t; e<7040; e+=256){
        const int ci = e/220, rem = e%220, rr = rem/20, col = rem%20;
        const float v = in[ibase + ci*25600 + (p0+rr)*160 + col];
        s[ci*264 + (sr0+rr)*22 + (col+1)] = fmaxf(fmaf(v, sc[ci], sh[ci]), 0.f);
    }
    __syncthreads();
    const int c = t & 31, tile = t >> 5;
    const int r0 = (tile >> 2)*5, c0 = (tile & 3)*5;
    float acc[5][5];
    { const float bv = P[OFF_RLCB + net*32 + c];
      #pragma unroll
      for (int rr=0;rr<5;rr++)
          #pragma unroll
          for (int cc=0;cc<5;cc++) acc[rr][cc]=bv; }
    #pragma unroll 1
    for (int ci=0; ci<32; ci++){
        float win[7][7];
        const float* sp = &s[ci*264 + r0*22 + c0];
        #pragma unroll
        for (int i7=0;i7<7;i7++)
            #pragma unroll
            for (int j7=0;j7<7;j7++) win[i7][j7] = sp[i7*22+j7];
        float wv[9];
        const bf16* wp = &wsm[ci*288 + c];
        #pragma unroll
        for (int q=0;q<9;q++) wv[q] = b2f(wp[q*32]);
        #pragma unroll
        for (int rr=0;rr<5;rr++)
            #pragma unroll
            for (int dy=0;dy<3;dy++)
                #pragma unroll
                for (int dx=0;dx<3;dx++){
                    const float wq = wv[dy*3+dx];
                    #pragma unroll
                    for (int cc=0;cc<5;cc++)
                        acc[rr][cc] = fmaf(win[rr+dy][cc+dx], wq, acc[rr][cc]);
                }
    }
    __syncthreads();
    {
        const int obase = ibase + c*25600 + (h*10 + r0)*160 + c0;
        #pragma unroll
        for (int rr=0;rr<5;rr++)
            #pragma unroll
            for (int cc=0;cc<5;cc++)
                s[c*200 + (r0+rr)*20 + (c0+cc)] = acc[rr][cc] + in[obase + rr*160 + cc];
    }
    __syncthreads();
    for (int e=t; e<1600; e+=256){
        const int c2 = e/50, rem = e%50, pr = rem/10, pc = rem%10;
        const float* sp = &s[c2*200 + (2*pr)*20 + 2*pc];
        float m = fmaxf(fmaxf(sp[0],sp[1]), fmaxf(sp[20],sp[21]));
        m = fmaxf(m, 0.f);
        const float inv = rsqrtf(P[OFF_BNV + c2] + 1e-5f) * P[OFF_BNG + c2];
        pooled[((b*32+c2)*80 + gi*10 + h*5 + pr)*80 + gj*10 + pc] =
            fmaf(m - P[OFF_BNM + c2], inv, P[OFF_BNB + c2]);
    }
}

// ------- conv2/conv3 via MFMA shift-GEMM (validated in R3) -------
template<int CIN, int HIN, int WIN, int HOUT, int WOUT>
__global__ __launch_bounds__(256) void k_convM(const float* __restrict__ in,
        const unsigned short* __restrict__ WB, const float* __restrict__ bias,
        float* __restrict__ out)
{
    constexpr int PP = 23;
    constexpr bool C32 = (CIN == 32);
    __shared__ unsigned short xs[PP*PP*CIN];           // [pix][ci] bf16
    __shared__ unsigned short ws[C32 ? 16*64*8 : 32*64*8];
    const int t = threadIdx.x;
    const int col0 = blockIdx.x*16, row0 = blockIdx.y*16, b = blockIdx.z;
    for (int e = t; e < PP*PP*(CIN/2); e += 256){
        const int ci2 = e % (CIN/2), pix = e / (CIN/2);
        int rr = row0 + pix/PP; if (rr > HIN-1) rr = HIN-1;
        int cc = col0 + pix%PP; if (cc > WIN-1) cc = WIN-1;
        const float* gp = &in[((long)(b*CIN + 2*ci2)*HIN + rr)*WIN + cc];
        const unsigned lo = f2bf_u(gp[0]);
        const unsigned hi = f2bf_u(gp[(long)HIN*WIN]);
        ((unsigned*)xs)[pix*(CIN/2) + ci2] = lo | (hi << 16);
    }
    const int wave = t>>6, lane = t&63;
    const int quad = lane>>4, n16 = lane&15;
    const float bv = bias[n16];
    f32x4 acc[4];
    #pragma unroll
    for (int mt=0;mt<4;mt++) acc[mt] = (f32x4){bv,bv,bv,bv};
    if constexpr (C32){
        for (int ch=0; ch<4; ch++){
            __syncthreads();
            const unsigned* src = (const unsigned*)WB + ch*4096;
            for (int e=t; e<4096; e+=256) ((unsigned*)ws)[e] = src[e];
            __syncthreads();
            #pragma unroll 1
            for (int tap=0; tap<16; tap++){
                const int tg = ch*16+tap, ky = tg>>3, kx = tg&7;
                const short8 bw = *(const short8*)&ws[(tap*64+lane)*8];
                #pragma unroll
                for (int mt=0; mt<4; mt++){
                    const int pr = wave*4+mt+ky, pc = n16+kx;
                    const short8 av = *(const short8*)&xs[(pr*PP+pc)*32 + quad*8];
                    acc[mt] = __builtin_amdgcn_mfma_f32_16x16x32_bf16(av, bw, acc[mt], 0,0,0);
                }
            }
        }
    } else {
        for (int e=t; e<8192; e+=256) ((unsigned*)ws)[e] = ((const unsigned*)WB)[e];
        __syncthreads();
        #pragma unroll 1
        for (int pair=0; pair<32; pair++){
            const int ky = pair>>2, kx0 = (pair&3)*2;
            const short8 bw = *(const short8*)&ws[(pair*64+lane)*8];
            #pragma unroll
            for (int mt=0; mt<4; mt++){
                const int pr = wave*4+mt+ky, pc = n16 + kx0 + (quad>>1);
                const short8 av = *(const short8*)&xs[(pr*PP+pc)*16 + (quad&1)*8];
                acc[mt] = __builtin_amdgcn_mfma_f32_16x16x32_bf16(av, bw, acc[mt], 0,0,0);
            }
        }
    }
    #pragma unroll
    for (int mt=0; mt<4; mt++){
        const int orow = row0 + wave*4 + mt;
        if (orow >= HOUT) continue;
        const int ocol = col0 + quad*4;
        float* op = out + ((long)(b*16 + n16)*HOUT + orow)*WOUT + ocol;
        #pragma unroll
        for (int r=0;r<4;r++){
            if (ocol + r < WOUT) op[r] = fmaxf(acc[mt][r], 0.f);
        }
    }
}

// ---------------- generic direct conv (+relu) for the small conv4/conv5 ----------------
template<int CIN, int COUT, int KS, int STRIDE, int HIN, int WIN, int HOUT, int WOUT, int NG>
__global__ __launch_bounds__(256) void k_convN(const float* __restrict__ in,
        const float* __restrict__ w, const float* __restrict__ bias, float* __restrict__ out)
{
    __shared__ float wl[CIN*KS*KS];
    const int co = blockIdx.y, b = blockIdx.z;
    for (int j=threadIdx.x; j<CIN*KS*KS; j+=blockDim.x) wl[j] = w[co*CIN*KS*KS + j];
    __syncthreads();
    const int i = blockIdx.x*blockDim.x + threadIdx.x;
    if (i >= HOUT*NG) return;
    const int y = i / NG, x0 = (i % NG) * 8;
    float acc[8];
    const float bv = bias[co];
    #pragma unroll
    for (int j=0;j<8;j++) acc[j]=bv;
    constexpr int SPAN = STRIDE*7 + KS;
    for (int ci=0; ci<CIN; ci++){
        #pragma unroll 1
        for (int ky=0; ky<KS; ky++){
            const float* ip = in + ((b*CIN+ci)*HIN + (STRIDE*y+ky))*WIN + STRIDE*x0;
            float v[SPAN];
            #pragma unroll
            for (int j=0;j<SPAN;j++) v[j]=ip[j];
            const float* wr = &wl[(ci*KS+ky)*KS];
            #pragma unroll
            for (int kx=0;kx<KS;kx++){
                const float wv = wr[kx];
                #pragma unroll
                for (int j=0;j<8;j++) acc[j] = fmaf(v[STRIDE*j+kx], wv, acc[j]);
            }
        }
    }
    float* op = out + ((b*COUT+co)*HOUT + y)*WOUT + x0;
    #pragma unroll
    for (int j=0;j<8;j++){
        if (x0 + j < WOUT) op[j] = fmaxf(acc[j], 0.f);
    }
}

// ---------------- FC via MFMA: y[32,N] (+)= x[32,K] @ w[N,K]^T ----------------
// wave = 16-batch x 16-output tile; K-split across blockIdx.y; f32 atomicAdd epilogue.
__global__ void k_binit(float* __restrict__ y, const float* __restrict__ bias, int N)
{
    const int i = blockIdx.x*256 + threadIdx.x;
    if (i < 32*N) y[i] = bias[i % N];
}

template<typename WT>
__device__ __forceinline__ void fcm_loop(const float* __restrict__ xp, const WT* __restrict__ wp,
        int start, int end, int quad, int relu_in, f32x4& acc)
{
    const int end32 = start + ((end - start) & ~31);
    for (int k0 = start; k0 < end32; k0 += 32){
        const int ka = k0 + quad*8;
        float xv[8];
        *(f32x4*)&xv[0] = *(const f32x4*)&xp[ka];
        *(f32x4*)&xv[4] = *(const f32x4*)&xp[ka+4];
        if (relu_in){
            #pragma unroll
            for (int j=0;j<8;j++) xv[j] = fmaxf(xv[j], 0.f);
        }
        short8 bw;
        if constexpr (__is_same(WT, bf16)){
            bw = *(const short8*)&wp[ka];
        } else {
            float wv[8];
            *(f32x4*)&wv[0] = *(const f32x4*)&wp[ka];
            *(f32x4*)&wv[4] = *(const f32x4*)&wp[ka+4];
            bw = pack8(wv);
        }
        acc = __builtin_amdgcn_mfma_f32_16x16x32_bf16(pack8(xv), bw, acc, 0,0,0);
    }
    if (end32 < end){
        const int ka = end32 + quad*8;
        float xv[8], wv[8];
        #pragma unroll
        for (int j=0;j<8;j++){
            const bool v = (ka + j) < end;
            xv[j] = v ? xp[ka+j] : 0.f;
            wv[j] = v ? (float)ld(wp, ka+j) : 0.f;
            if (relu_in) xv[j] = fmaxf(xv[j], 0.f);
        }
        acc = __builtin_amdgcn_mfma_f32_16x16x32_bf16(pack8(xv), pack8(wv), acc, 0,0,0);
    }
}

__global__ __launch_bounds__(256) void k_fcM(const float* __restrict__ x,
        const void* __restrict__ w, const int* __restrict__ flag,
        float* __restrict__ y, int K, int N, int Kc, int relu_in, int Nvalid)
{
    const int t = threadIdx.x;
    const int wave = t>>6, lane = t&63;
    const int quad = lane>>4, n16 = lane&15;
    const int og = wave>>1, bh = wave&1;
    const int o = blockIdx.x*32 + og*16 + n16;
    const int orow = (o < Nvalid) ? o : (Nvalid-1);
    const int xrow = bh*16 + n16;
    const int start = blockIdx.y*Kc;
    const int end = min(K, start + Kc);
    f32x4 acc = {0.f,0.f,0.f,0.f};
    const float* xp = x + (long)xrow*K;
    if (*flag) fcm_loop<float>(xp, (const float*)w + (long)orow*K, start, end, quad, relu_in, acc);
    else       fcm_loop<bf16 >(xp, (const bf16 *)w + (long)orow*K, start, end, quad, relu_in, acc);
    if (o < Nvalid){
        #pragma unroll
        for (int r=0;r<4;r++)
            atomicAdd(&y[(long)(bh*16 + quad*4 + r)*N + o], acc[r]);
    }
}

// ---------------- paired log_softmax over axis 1 of [32,2,12] ----------------
__global__ void k_lsm(const float* __restrict__ in, const int* __restrict__ flag,
                      void* __restrict__ out)
{
    const int i = threadIdx.x;
    if (i >= 384) return;
    const int b = i/12, au = i%12;
    const float a0 = in[b*24+au], a1 = in[b*24+12+au];
    const float m = fmaxf(a0,a1);
    const float lse = m + logf(expf(a0-m)+expf(a1-m));
    const float o0 = a0-lse, o1 = a1-lse;
    if (*flag){
        ((float*)out)[b*24+au]    = o0;
        ((float*)out)[b*24+12+au] = o1;
    } else {
        ((bf16*)out)[b*24+au]    = __float2bfloat16(o0);
        ((bf16*)out)[b*24+12+au] = __float2bfloat16(o1);
    }
}

extern "C" void kernel_launch(void* const* d_in, const int* in_sizes, int n_in,
                              void* d_out, int out_size, void* d_ws, size_t ws_size,
                              hipStream_t stream) {
    (void)in_sizes; (void)n_in; (void)out_size; (void)ws_size;
    const void* x = d_in[0];

    float* A = (float*)d_ws;               // 26,214,400 floats
    float* B = A + 26214400;               //  6,553,600 floats
    float* P = B + 6553600;                //  P_END floats
    int* flag = (int*)(P + P_END);

    CvtArgs a;
    const int src_idx[23] = {1,2,3,4,5,6,7,8,9,10,11,12,13,14,15,16,17,18,19,20,22,24,26};
    const int offs[23] = {OFF_C1W,OFF_C1B,OFF_RLG,OFF_RLB,OFF_RLM,OFF_RLV,OFF_RLCW,OFF_RLCB,
                          OFF_BNG,OFF_BNB,OFF_BNM,OFF_BNV,OFF_C2W,OFF_C2B,OFF_C3W,OFF_C3B,
                          OFF_C4W,OFF_C4B,OFF_C5W,OFF_C5B,OFF_F1B,OFF_F2B,OFF_F3B};
    for (int j=0;j<23;j++){ a.src[j] = d_in[src_idx[j]]; a.off[j] = offs[j]; }
    a.cw = d_in[7]; a.w2 = d_in[13]; a.w3 = d_in[15];
    a.total = P_TOTAL;

    k_sniff<<<1,256,0,stream>>>(x, flag);
    k_cvt<<<(P_TOTAL+SZ_RL+SZ_WB2+SZ_WB3+255)/256,256,0,stream>>>(a, flag, P);
    k_conv1<<<dim3(40,32,2),256,0,stream>>>(x, flag, P, A);
    k_region_pool<<<4096,256,0,stream>>>(A, P, B);
    // conv2: [32,32,80,80] -> [32,16,73,73]  (MFMA)
    k_convM<32,80,80,73,73><<<dim3(5,5,32),256,0,stream>>>(B, (const unsigned short*)(P+OFF_WB2), P+OFF_C2B, A);
    // conv3: -> [32,16,66,66]  (MFMA)
    k_convM<16,73,73,66,66><<<dim3(5,5,32),256,0,stream>>>(A, (const unsigned short*)(P+OFF_WB3), P+OFF_C3B, B);
    // conv4: stride 2 -> [32,16,31,31]
    k_convN<16,16,6,2,66,66,31,31,4><<<dim3(1,16,32),128,0,stream>>>(B, P+OFF_C4W, P+OFF_C4B, A);
    // conv5: -> [32,16,27,27]
    k_convN<16,16,5,1,31,31,27,27,4><<<dim3(1,16,32),128,0,stream>>>(A, P+OFF_C5W, P+OFF_C5B, B);
    // fc1: K=11664 -> 4096; x=B (relu already applied by conv5), y=A
    k_binit<<<(32*4096+255)/256,256,0,stream>>>(A, P+OFF_F1B, 4096);
    k_fcM<<<dim3(128,4),256,0,stream>>>(B, d_in[21], flag, A, 11664, 4096, 2912, 0, 4096);
    // fc2: K=4096 -> 2048; x=A with relu-on-load, y=B
    k_binit<<<(32*2048+255)/256,256,0,stream>>>(B, P+OFF_F2B, 2048);
    k_fcM<<<dim3(64,8),256,0,stream>>>(A, d_in[23], flag, B, 4096, 2048, 512, 1, 2048);
    // fc3: K=2048 -> 24; x=B with relu-on-load, y=A (stride 24)
    k_binit<<<(32*24+255)/256,256,0,stream>>>(A, P+OFF_F3B, 24);
    k_fcM<<<dim3(1,64),256,0,stream>>>(B, d_in[25], flag, A, 2048, 24, 32, 1, 24);
    k_lsm<<<1,384,0,stream>>>(A, flag, d_out);
}

// Round 6
// 762.170 us; speedup vs baseline: 4.3107x; 1.4050x over previous
//
#include <hip/hip_runtime.h>
#include <hip/hip_bf16.h>

typedef __hip_bfloat16 bf16;
typedef __attribute__((ext_vector_type(8))) short short8;
typedef __attribute__((ext_vector_type(4))) float f32x4;
typedef __attribute__((ext_vector_type(16))) float f32x16;

__device__ __forceinline__ float b2f(const bf16 v){ return __bfloat162float(v); }
__device__ __forceinline__ float ld(const float* p, long i){ return p[i]; }
__device__ __forceinline__ float ld(const bf16*  p, long i){ return b2f(p[i]); }

__device__ __forceinline__ unsigned f2bf_u(float f){
    union { float f; unsigned u; } a; a.f = f;
    unsigned r = a.u + 0x7FFFu + ((a.u >> 16) & 1u);
    return r >> 16;
}

__device__ __forceinline__ short8 pack8(const float* v){
    union { unsigned u[4]; short8 s; } r;
    r.u[0] = f2bf_u(v[0]) | (f2bf_u(v[1])<<16);
    r.u[1] = f2bf_u(v[2]) | (f2bf_u(v[3])<<16);
    r.u[2] = f2bf_u(v[4]) | (f2bf_u(v[5])<<16);
    r.u[3] = f2bf_u(v[6]) | (f2bf_u(v[7])<<16);
    return r.s;
}

// ---- converted-params block offsets (floats) within P ----
#define OFF_C1W   0        /* 11616 */
#define OFF_C1B   11616    /* 32   */
#define OFF_RLG   11648    /* 2048 */
#define OFF_RLB   13696
#define OFF_RLM   15744
#define OFF_RLV   17792
#define OFF_RLCW  19840    /* 589824 slots: bf16 WR [net][tap9][half2][lane64][j8] */
#define OFF_RLCB  609664   /* 2048 */
#define OFF_BNG   611712
#define OFF_BNB   611744
#define OFF_BNM   611776
#define OFF_BNV   611808
#define OFF_C2W   611840   /* 32768 */
#define OFF_C2B   644608
#define OFF_C3W   644624   /* 16384 */
#define OFF_C3B   661008
#define OFF_C4W   661024   /* 9216 */
#define OFF_C4B   670240
#define OFF_C5W   670256   /* 6400 */
#define OFF_C5B   676656
#define OFF_F1B   676672   /* 4096 */
#define OFF_F2B   680768   /* 2048 */
#define OFF_F3B   682816   /* 24   */
#define P_TOTAL   682840
#define OFF_WB2   P_TOTAL             /* 32768 bf16 = 16384 f32 slots */
#define OFF_WB3   (P_TOTAL + 16384)   /* 16384 bf16 = 8192 f32 slots  */
#define OFF_WC1   (P_TOTAL + 16384 + 8192)  /* 16896 bf16 = 8448 f32 slots */
#define P_END     (OFF_WC1 + 8448)

#define SZ_RL  589824
#define SZ_WB2 32768
#define SZ_WB3 16384
#define SZ_WC1 16896

// ---------- dtype sniff: flag=1 if inputs are float32, 0 if bf16 ----------
__global__ void k_sniff(const void* __restrict__ x, int* __restrict__ flag)
{
    const bf16* xb = (const bf16*)x;
    const float v = fabsf(b2f(xb[2*threadIdx.x]));
    const int ok = (v >= 1e-6f && v <= 1e6f) ? 1 : 0;
    __shared__ int cnt;
    if (threadIdx.x == 0) cnt = 0;
    __syncthreads();
    atomicAdd(&cnt, ok);
    __syncthreads();
    if (threadIdx.x == 0) *flag = (cnt >= 192) ? 0 : 1;
}

// ---------- convert params to f32 block P + bf16 fragment-layout weight blocks ----------
struct CvtArgs { const void* src[23]; int off[23]; const void* cw; const void* w2; const void* w3; int total; };

__device__ __forceinline__ float getv(const void* p, long i, bool isf){
    return isf ? ((const float*)p)[i] : b2f(((const bf16*)p)[i]);
}

__global__ __launch_bounds__(256) void k_cvt(CvtArgs a, const int* __restrict__ flag,
                                             float* __restrict__ P)
{
    const bool isf = (*flag != 0);
    const int i1 = a.total;            // region WR frags (bf16, in rl_cw slot)
    const int i2 = i1 + SZ_RL;         // WB2
    const int i3 = i2 + SZ_WB2;        // WB3
    const int i4 = i3 + SZ_WB3;        // WC1
    const int i5 = i4 + SZ_WC1;
    for (int idx = blockIdx.x*256 + threadIdx.x; idx < i5; idx += gridDim.x*256){
        if (idx < i1){
            if (idx >= OFF_RLCW && idx < OFF_RLCB) continue;   // slot reused for WR
            int k = 0;
            #pragma unroll
            for (int j = 1; j < 23; j++) if (idx >= a.off[j]) k = j;
            P[idx] = getv(a.src[k], idx - a.off[k], isf);
        } else if (idx < i2){
            // WR[net][tap][half][lane][j]: A-frag (weights, M=co16) for region
            const int d = idx - i1;
            const int net = d / 9216, dn = d % 9216;
            const int tap = dn >> 10, rem = dn & 1023;
            const int half = rem >> 9, lane = (rem >> 3) & 63, j = rem & 7;
            const int co = half*16 + (lane & 15);
            const int ci = ((lane >> 4) << 3) + j;
            const long sidx = (long)((net*32 + co)*32 + ci)*9 + tap;
            ((unsigned short*)(P + OFF_RLCW))[d] = (unsigned short)f2bf_u(getv(a.cw, sidx, isf));
        } else if (idx < i3){
            // WB2[tap][lane][j]: B-frag layout for conv2 (K=32ci)
            const int d = idx - i2;
            const int j = d & 7, lane = (d >> 3) & 63, tap = d >> 9;
            const int n = lane & 15, k = ((lane >> 4) << 3) + j;
            const int ci = k, ky = tap >> 3, kx = tap & 7;
            const long sidx = (long)((n*32 + ci)*8 + ky)*8 + kx;
            ((unsigned short*)(P + OFF_WB2))[d] = (unsigned short)f2bf_u(getv(a.w2, sidx, isf));
        } else if (idx < i4){
            // WB3[pair][lane][j]: B-frag layout for conv3 (K=16ci x 2 taps)
            const int d = idx - i3;
            const int j = d & 7, lane = (d >> 3) & 63, pair = d >> 9;
            const int n = lane & 15, k = ((lane >> 4) << 3) + j;
            const int tsel = k >> 4, ci = k & 15;
            const int ky = pair >> 2, kx = ((pair & 3) << 1) + tsel;
            const long sidx = (long)((n*16 + ci)*8 + ky)*8 + kx;
            ((unsigned short*)(P + OFF_WB3))[d] = (unsigned short)f2bf_u(getv(a.w3, sidx, isf));
        } else {
            // WC1[ky][ch][lane][j]: A-frag (weights, M=co32) for conv1, K=16 = 4kx x 4ci
            const int d = idx - i4;
            const int ky = d / 1536, rem = d % 1536;
            const int ch = rem >> 9, rem2 = rem & 511;
            const int lane = rem2 >> 3, j = rem2 & 7;
            const int co = lane & 31, h5 = lane >> 5;
            const int kx = ch*4 + h5*2 + (j >> 2), ci = j & 3;
            float v = 0.f;
            if (ci < 3 && kx < 11)
                v = getv(a.src[0], (long)((co*3 + ci)*11 + ky)*11 + kx, isf);
            ((unsigned short*)(P + OFF_WC1))[d] = (unsigned short)f2bf_u(v);
        }
    }
}

// ---------------- conv1 via 32x32x16 MFMA: x[32,3,170,170] -> [32,32,160,160] ----------------
// block = (8-row group, 32-col tile, b); wave = 2 row-strips; A=W[co32][k16], B=X[k16][pix32]
__global__ __launch_bounds__(256,3) void k_conv1M(const void* __restrict__ x,
        const int* __restrict__ flag, const float* __restrict__ P, float* __restrict__ out)
{
    __shared__ unsigned short xs[18*44*4];     // [row18][col44][ci4] bf16, 6336 B
    __shared__ unsigned short wsm[SZ_WC1];     // 33792 B
    const int t = threadIdx.x;
    const int y0 = blockIdx.x*8, x0 = blockIdx.y*32, b = blockIdx.z;
    { const uint4* src = (const uint4*)(P + OFF_WC1);
      uint4* dst = (uint4*)wsm;
      for (int e=t; e<2112; e+=256) dst[e] = src[e]; }
    const bool isf = (*flag) != 0;
    for (int e=t; e<792; e+=256){
        const int r = e/44, c = e%44;
        const long base = ((long)(b*3)*170 + (y0+r))*170 + min(x0+c, 169);
        float v0, v1, v2;
        if (isf){
            const float* xf = (const float*)x;
            v0 = xf[base]; v1 = xf[base+28900]; v2 = xf[base+57800];
        } else {
            const bf16* xf = (const bf16*)x;
            v0 = b2f(xf[base]); v1 = b2f(xf[base+28900]); v2 = b2f(xf[base+57800]);
        }
        uint2 u;
        u.x = f2bf_u(v0) | (f2bf_u(v1) << 16);
        u.y = f2bf_u(v2);
        *(uint2*)&xs[(r*44+c)*4] = u;
    }
    __syncthreads();
    const int wave = t>>6, lane = t&63;
    const int n = lane & 31, h5 = lane >> 5;
    const int r0 = wave*2;
    f32x16 acc0 = {0.f}, acc1 = {0.f};
    #pragma unroll
    for (int e=0;e<16;e++){ acc0[e]=0.f; acc1[e]=0.f; }
    #pragma unroll 1
    for (int ky=0; ky<11; ky++){
        #pragma unroll
        for (int ch=0; ch<3; ch++){
            const short8 aw = *(const short8*)&wsm[((ky*3+ch)*64 + lane)*8];
            const int kx0 = ch*4 + h5*2;
            const int a0 = ((r0+ky)*44 + n + kx0)*4;
            const int a1 = ((r0+1+ky)*44 + n + kx0)*4;
            union { uint2 u2[2]; short8 s; } ub0, ub1;
            ub0.u2[0] = *(const uint2*)&xs[a0];
            ub0.u2[1] = *(const uint2*)&xs[a0+4];
            ub1.u2[0] = *(const uint2*)&xs[a1];
            ub1.u2[1] = *(const uint2*)&xs[a1+4];
            acc0 = __builtin_amdgcn_mfma_f32_32x32x16_bf16(aw, ub0.s, acc0, 0,0,0);
            acc1 = __builtin_amdgcn_mfma_f32_32x32x16_bf16(aw, ub1.s, acc1, 0,0,0);
        }
    }
    // D: col = lane&31 = pixel-col, row(co) = (reg&3) + 8*(reg>>2) + 4*h5
    #pragma unroll
    for (int reg=0; reg<16; reg++){
        const int co = (reg&3) + 8*(reg>>2) + 4*h5;
        const float bv = P[OFF_C1B + co];
        float* op = out + ((long)(b*32+co)*160 + (y0+r0))*160 + x0 + n;
        op[0]   = acc0[reg] + bv;
        op[160] = acc1[reg] + bv;
    }
}

// ------- region layer via 16x16x32 MFMA, fused relu+maxpool2+bn with shuffle pooling -------
// block = (patch, batch); A=W[co16][ci32] (2 halves), B=X[ci32][pix16] (4x4 tiles)
__global__ __launch_bounds__(256,2) void k_regionM(const float* __restrict__ in,
        const float* __restrict__ P, float* __restrict__ pooled)
{
    __shared__ unsigned short s_in[484*32];    // [pix 22x22][ci32] bf16, 30976 B
    __shared__ unsigned short wsm[9216];       // [tap9][half2][lane64][j8], 18432 B
    __shared__ float sc[32], sh[32];
    const int t = threadIdx.x;
    const int b = blockIdx.x & 31, kk = blockIdx.x >> 5;
    const int gi = kk >> 3, gj = kk & 7;
    const int net = gj*(gi+1);                 // idx = ii*jj + jj
    const int ibase = (b*32*160 + gi*20)*160 + gj*20;
    if (t < 32){
        const float inv = rsqrtf(P[OFF_RLV+net*32+t]+1e-5f)*P[OFF_RLG+net*32+t];
        sc[t] = inv; sh[t] = P[OFF_RLB+net*32+t] - P[OFF_RLM+net*32+t]*inv;
    }
    { const uint4* src = (const uint4*)((const unsigned short*)(P+OFF_RLCW) + (size_t)net*9216);
      uint4* dst = (uint4*)wsm;
      for (int e=t; e<1152; e+=256) dst[e] = src[e]; }
    __syncthreads();
    // stage BN+ReLU patch, zero halo: item = (pixel, ci-oct) -> one b128 LDS write
    for (int e=t; e<1936; e+=256){
        const int o = e & 3, p = e >> 2;
        const int pr = p/22, pc = p%22;
        unsigned ov[4] = {0u,0u,0u,0u};
        if (pr>0 && pr<21 && pc>0 && pc<21){
            const int base = ibase + (pr-1)*160 + (pc-1);
            #pragma unroll
            for (int q2=0;q2<4;q2++){
                const int ci0 = o*8 + q2*2;
                float v0 = in[base + ci0*25600];
                float v1 = in[base + (ci0+1)*25600];
                v0 = fmaxf(fmaf(v0, sc[ci0],   sh[ci0]),   0.f);
                v1 = fmaxf(fmaf(v1, sc[ci0+1], sh[ci0+1]), 0.f);
                ov[q2] = f2bf_u(v0) | (f2bf_u(v1) << 16);
            }
        }
        *(uint4*)&s_in[p*32 + o*8] = *(const uint4*)ov;
    }
    __syncthreads();
    const int wave = t>>6, lane = t&63;
    const int q = lane>>4, n = lane&15;
    const int dr = n>>2, dc = n&3;
    const int nt = (wave==0) ? 7 : 6;          // 25 tiles over 4 waves
    int trs[7], tcs[7];
    #pragma unroll
    for (int i=0;i<7;i++){ const int tt = 4*i + wave; trs[i] = tt/5; tcs[i] = tt - 5*(tt/5); }
    f32x4 acc[7][2];
    {   float bias_v[2][4];
        #pragma unroll
        for (int h=0;h<2;h++)
            #pragma unroll
            for (int r=0;r<4;r++) bias_v[h][r] = P[OFF_RLCB + net*32 + h*16 + q*4 + r];
        #pragma unroll
        for (int i=0;i<7;i++)
            #pragma unroll
            for (int h=0;h<2;h++)
                acc[i][h] = (f32x4){bias_v[h][0], bias_v[h][1], bias_v[h][2], bias_v[h][3]};
    }
    #pragma unroll 1
    for (int tap=0; tap<9; tap++){
        const int ky = tap/3, kx = tap - 3*(tap/3);
        const short8 a0 = *(const short8*)&wsm[(tap*2+0)*512 + lane*8];
        const short8 a1 = *(const short8*)&wsm[(tap*2+1)*512 + lane*8];
        #pragma unroll
        for (int i=0;i<7;i++){
            if (i < nt){
                const int srow = trs[i]*4 + dr + ky, scol = tcs[i]*4 + dc + kx;
                const short8 bx = *(const short8*)&s_in[(srow*22 + scol)*32 + q*8];
                acc[i][0] = __builtin_amdgcn_mfma_f32_16x16x32_bf16(a0, bx, acc[i][0], 0,0,0);
                acc[i][1] = __builtin_amdgcn_mfma_f32_16x16x32_bf16(a1, bx, acc[i][1], 0,0,0);
            }
        }
    }
    // epilogue: residual + relu + 2x2 shuffle-pool + bn;  D: col=n=pixel, row=co=q*4+reg
    float bnsc[2][4], bnsh[2][4];
    #pragma unroll
    for (int h=0;h<2;h++)
        #pragma unroll
        for (int r=0;r<4;r++){
            const int co = h*16 + q*4 + r;
            const float inv = rsqrtf(P[OFF_BNV+co]+1e-5f)*P[OFF_BNG+co];
            bnsc[h][r] = inv; bnsh[h][r] = P[OFF_BNB+co] - P[OFF_BNM+co]*inv;
        }
    const bool wr = ((n & 5) == 0);            // dc even && dr even
    #pragma unroll
    for (int i=0;i<7;i++){
        if (i < nt){
            const int prow = trs[i]*4 + dr, pcol = tcs[i]*4 + dc;
            #pragma unroll
            for (int h=0;h<2;h++){
                #pragma unroll
                for (int r=0;r<4;r++){
                    const int co = h*16 + q*4 + r;
                    float v = acc[i][h][r] + in[ibase + co*25600 + prow*160 + pcol];
                    v = fmaxf(v, 0.f);
                    v = fmaxf(v, __shfl_xor(v, 1, 64));
                    v = fmaxf(v, __shfl_xor(v, 4, 64));
                    if (wr){
                        pooled[((b*32+co)*80 + gi*10 + trs[i]*2 + (dr>>1))*80
                               + gj*10 + tcs[i]*2 + (dc>>1)] = fmaf(v, bnsc[h][r], bnsh[h][r]);
                    }
                }
            }
        }
    }
}

// ------- conv2/conv3 via MFMA shift-GEMM (validated in R3) -------
template<int CIN, int HIN, int WIN, int HOUT, int WOUT>
__global__ __launch_bounds__(256) void k_convM(const float* __restrict__ in,
        const unsigned short* __restrict__ WB, const float* __restrict__ bias,
        float* __restrict__ out)
{
    constexpr int PP = 23;
    constexpr bool C32 = (CIN == 32);
    __shared__ unsigned short xs[PP*PP*CIN];
    __shared__ unsigned short ws[C32 ? 16*64*8 : 32*64*8];
    const int t = threadIdx.x;
    const int col0 = blockIdx.x*16, row0 = blockIdx.y*16, b = blockIdx.z;
    for (int e = t; e < PP*PP*(CIN/2); e += 256){
        const int ci2 = e % (CIN/2), pix = e / (CIN/2);
        int rr = row0 + pix/PP; if (rr > HIN-1) rr = HIN-1;
        int cc = col0 + pix%PP; if (cc > WIN-1) cc = WIN-1;
        const float* gp = &in[((long)(b*CIN + 2*ci2)*HIN + rr)*WIN + cc];
        const unsigned lo = f2bf_u(gp[0]);
        const unsigned hi = f2bf_u(gp[(long)HIN*WIN]);
        ((unsigned*)xs)[pix*(CIN/2) + ci2] = lo | (hi << 16);
    }
    const int wave = t>>6, lane = t&63;
    const int quad = lane>>4, n16 = lane&15;
    const float bv = bias[n16];
    f32x4 acc[4];
    #pragma unroll
    for (int mt=0;mt<4;mt++) acc[mt] = (f32x4){bv,bv,bv,bv};
    if constexpr (C32){
        for (int ch=0; ch<4; ch++){
            __syncthreads();
            const unsigned* src = (const unsigned*)WB + ch*4096;
            for (int e=t; e<4096; e+=256) ((unsigned*)ws)[e] = src[e];
            __syncthreads();
            #pragma unroll 1
            for (int tap=0; tap<16; tap++){
                const int tg = ch*16+tap, ky = tg>>3, kx = tg&7;
                const short8 bw = *(const short8*)&ws[(tap*64+lane)*8];
                #pragma unroll
                for (int mt=0; mt<4; mt++){
                    const int pr = wave*4+mt+ky, pc = n16+kx;
                    const short8 av = *(const short8*)&xs[(pr*PP+pc)*32 + quad*8];
                    acc[mt] = __builtin_amdgcn_mfma_f32_16x16x32_bf16(av, bw, acc[mt], 0,0,0);
                }
            }
        }
    } else {
        for (int e=t; e<8192; e+=256) ((unsigned*)ws)[e] = ((const unsigned*)WB)[e];
        __syncthreads();
        #pragma unroll 1
        for (int pair=0; pair<32; pair++){
            const int ky = pair>>2, kx0 = (pair&3)*2;
            const short8 bw = *(const short8*)&ws[(pair*64+lane)*8];
            #pragma unroll
            for (int mt=0; mt<4; mt++){
                const int pr = wave*4+mt+ky, pc = n16 + kx0 + (quad>>1);
                const short8 av = *(const short8*)&xs[(pr*PP+pc)*16 + (quad&1)*8];
                acc[mt] = __builtin_amdgcn_mfma_f32_16x16x32_bf16(av, bw, acc[mt], 0,0,0);
            }
        }
    }
    #pragma unroll
    for (int mt=0; mt<4; mt++){
        const int orow = row0 + wave*4 + mt;
        if (orow >= HOUT) continue;
        const int ocol = col0 + quad*4;
        float* op = out + ((long)(b*16 + n16)*HOUT + orow)*WOUT + ocol;
        #pragma unroll
        for (int r=0;r<4;r++){
            if (ocol + r < WOUT) op[r] = fmaxf(acc[mt][r], 0.f);
        }
    }
}

// ---------------- generic direct conv (+relu) for the small conv4/conv5 ----------------
template<int CIN, int COUT, int KS, int STRIDE, int HIN, int WIN, int HOUT, int WOUT, int NG>
__global__ __launch_bounds__(256) void k_convN(const float* __restrict__ in,
        const float* __restrict__ w, const float* __restrict__ bias, float* __restrict__ out)
{
    __shared__ float wl[CIN*KS*KS];
    const int co = blockIdx.y, b = blockIdx.z;
    for (int j=threadIdx.x; j<CIN*KS*KS; j+=blockDim.x) wl[j] = w[co*CIN*KS*KS + j];
    __syncthreads();
    const int i = blockIdx.x*blockDim.x + threadIdx.x;
    if (i >= HOUT*NG) return;
    const int y = i / NG, x0 = (i % NG) * 8;
    float acc[8];
    const float bv = bias[co];
    #pragma unroll
    for (int j=0;j<8;j++) acc[j]=bv;
    constexpr int SPAN = STRIDE*7 + KS;
    for (int ci=0; ci<CIN; ci++){
        #pragma unroll 1
        for (int ky=0; ky<KS; ky++){
            const float* ip = in + ((b*CIN+ci)*HIN + (STRIDE*y+ky))*WIN + STRIDE*x0;
            float v[SPAN];
            #pragma unroll
            for (int j=0;j<SPAN;j++) v[j]=ip[j];
            const float* wr = &wl[(ci*KS+ky)*KS];
            #pragma unroll
            for (int kx=0;kx<KS;kx++){
                const float wv = wr[kx];
                #pragma unroll
                for (int j=0;j<8;j++) acc[j] = fmaf(v[STRIDE*j+kx], wv, acc[j]);
            }
        }
    }
    float* op = out + ((b*COUT+co)*HOUT + y)*WOUT + x0;
    #pragma unroll
    for (int j=0;j<8;j++){
        if (x0 + j < WOUT) op[j] = fmaxf(acc[j], 0.f);
    }
}

// ---------------- FC via MFMA (validated in R4) ----------------
__global__ void k_binit(float* __restrict__ y, const float* __restrict__ bias, int N)
{
    const int i = blockIdx.x*256 + threadIdx.x;
    if (i < 32*N) y[i] = bias[i % N];
}

template<typename WT>
__device__ __forceinline__ void fcm_loop(const float* __restrict__ xp, const WT* __restrict__ wp,
        int start, int end, int quad, int relu_in, f32x4& acc)
{
    const int end32 = start + ((end - start) & ~31);
    for (int k0 = start; k0 < end32; k0 += 32){
        const int ka = k0 + quad*8;
        float xv[8];
        *(f32x4*)&xv[0] = *(const f32x4*)&xp[ka];
        *(f32x4*)&xv[4] = *(const f32x4*)&xp[ka+4];
        if (relu_in){
            #pragma unroll
            for (int j=0;j<8;j++) xv[j] = fmaxf(xv[j], 0.f);
        }
        short8 bw;
        if constexpr (__is_same(WT, bf16)){
            bw = *(const short8*)&wp[ka];
        } else {
            float wv[8];
            *(f32x4*)&wv[0] = *(const f32x4*)&wp[ka];
            *(f32x4*)&wv[4] = *(const f32x4*)&wp[ka+4];
            bw = pack8(wv);
        }
        acc = __builtin_amdgcn_mfma_f32_16x16x32_bf16(pack8(xv), bw, acc, 0,0,0);
    }
    if (end32 < end){
        const int ka = end32 + quad*8;
        float xv[8], wv[8];
        #pragma unroll
        for (int j=0;j<8;j++){
            const bool v = (ka + j) < end;
            xv[j] = v ? xp[ka+j] : 0.f;
            wv[j] = v ? (float)ld(wp, ka+j) : 0.f;
            if (relu_in) xv[j] = fmaxf(xv[j], 0.f);
        }
        acc = __builtin_amdgcn_mfma_f32_16x16x32_bf16(pack8(xv), pack8(wv), acc, 0,0,0);
    }
}

__global__ __launch_bounds__(256) void k_fcM(const float* __restrict__ x,
        const void* __restrict__ w, const int* __restrict__ flag,
        float* __restrict__ y, int K, int N, int Kc, int relu_in, int Nvalid)
{
    const int t = threadIdx.x;
    const int wave = t>>6, lane = t&63;
    const int quad = lane>>4, n16 = lane&15;
    const int og = wave>>1, bh = wave&1;
    const int o = blockIdx.x*32 + og*16 + n16;
    const int orow = (o < Nvalid) ? o : (Nvalid-1);
    const int xrow = bh*16 + n16;
    const int start = blockIdx.y*Kc;
    const int end = min(K, start + Kc);
    f32x4 acc = {0.f,0.f,0.f,0.f};
    const float* xp = x + (long)xrow*K;
    if (*flag) fcm_loop<float>(xp, (const float*)w + (long)orow*K, start, end, quad, relu_in, acc);
    else       fcm_loop<bf16 >(xp, (const bf16 *)w + (long)orow*K, start, end, quad, relu_in, acc);
    if (o < Nvalid){
        #pragma unroll
        for (int r=0;r<4;r++)
            atomicAdd(&y[(long)(bh*16 + quad*4 + r)*N + o], acc[r]);
    }
}

// ---------------- paired log_softmax over axis 1 of [32,2,12] ----------------
__global__ void k_lsm(const float* __restrict__ in, const int* __restrict__ flag,
                      void* __restrict__ out)
{
    const int i = threadIdx.x;
    if (i >= 384) return;
    const int b = i/12, au = i%12;
    const float a0 = in[b*24+au], a1 = in[b*24+12+au];
    const float m = fmaxf(a0,a1);
    const float lse = m + logf(expf(a0-m)+expf(a1-m));
    const float o0 = a0-lse, o1 = a1-lse;
    if (*flag){
        ((float*)out)[b*24+au]    = o0;
        ((float*)out)[b*24+12+au] = o1;
    } else {
        ((bf16*)out)[b*24+au]    = __float2bfloat16(o0);
        ((bf16*)out)[b*24+12+au] = __float2bfloat16(o1);
    }
}

extern "C" void kernel_launch(void* const* d_in, const int* in_sizes, int n_in,
                              void* d_out, int out_size, void* d_ws, size_t ws_size,
                              hipStream_t stream) {
    (void)in_sizes; (void)n_in; (void)out_size; (void)ws_size;
    const void* x = d_in[0];

    float* A = (float*)d_ws;               // 26,214,400 floats
    float* B = A + 26214400;               //  6,553,600 floats
    float* P = B + 6553600;                //  P_END floats
    int* flag = (int*)(P + P_END);

    CvtArgs a;
    const int src_idx[23] = {1,2,3,4,5,6,7,8,9,10,11,12,13,14,15,16,17,18,19,20,22,24,26};
    const int offs[23] = {OFF_C1W,OFF_C1B,OFF_RLG,OFF_RLB,OFF_RLM,OFF_RLV,OFF_RLCW,OFF_RLCB,
                          OFF_BNG,OFF_BNB,OFF_BNM,OFF_BNV,OFF_C2W,OFF_C2B,OFF_C3W,OFF_C3B,
                          OFF_C4W,OFF_C4B,OFF_C5W,OFF_C5B,OFF_F1B,OFF_F2B,OFF_F3B};
    for (int j=0;j<23;j++){ a.src[j] = d_in[src_idx[j]]; a.off[j] = offs[j]; }
    a.cw = d_in[7]; a.w2 = d_in[13]; a.w3 = d_in[15];
    a.total = P_TOTAL;

    k_sniff<<<1,256,0,stream>>>(x, flag);
    k_cvt<<<(P_TOTAL+SZ_RL+SZ_WB2+SZ_WB3+SZ_WC1+255)/256,256,0,stream>>>(a, flag, P);
    k_conv1M<<<dim3(20,5,32),256,0,stream>>>(x, flag, P, A);
    k_regionM<<<2048,256,0,stream>>>(A, P, B);
    // conv2: [32,32,80,80] -> [32,16,73,73]  (MFMA)
    k_convM<32,80,80,73,73><<<dim3(5,5,32),256,0,stream>>>(B, (const unsigned short*)(P+OFF_WB2), P+OFF_C2B, A);
    // conv3: -> [32,16,66,66]  (MFMA)
    k_convM<16,73,73,66,66><<<dim3(5,5,32),256,0,stream>>>(A, (const unsigned short*)(P+OFF_WB3), P+OFF_C3B, B);
    // conv4: stride 2 -> [32,16,31,31]
    k_convN<16,16,6,2,66,66,31,31,4><<<dim3(1,16,32),128,0,stream>>>(B, P+OFF_C4W, P+OFF_C4B, A);
    // conv5: -> [32,16,27,27]
    k_convN<16,16,5,1,31,31,27,27,4><<<dim3(1,16,32),128,0,stream>>>(A, P+OFF_C5W, P+OFF_C5B, B);
    // fc1: K=11664 -> 4096; x=B, y=A
    k_binit<<<(32*4096+255)/256,256,0,stream>>>(A, P+OFF_F1B, 4096);
    k_fcM<<<dim3(128,4),256,0,stream>>>(B, d_in[21], flag, A, 11664, 4096, 2912, 0, 4096);
    // fc2: K=4096 -> 2048; relu-on-load, y=B
    k_binit<<<(32*2048+255)/256,256,0,stream>>>(B, P+OFF_F2B, 2048);
    k_fcM<<<dim3(64,8),256,0,stream>>>(A, d_in[23], flag, B, 4096, 2048, 512, 1, 2048);
    // fc3: K=2048 -> 24; relu-on-load, y=A
    k_binit<<<(32*24+255)/256,256,0,stream>>>(A, P+OFF_F3B, 24);
    k_fcM<<<dim3(1,64),256,0,stream>>>(B, d_in[25], flag, A, 2048, 24, 32, 1, 24);
    k_lsm<<<1,384,0,stream>>>(A, flag, d_out);
}